// Round 1
// baseline (123.582 us; speedup 1.0000x reference)
//
#include <hip/hip_runtime.h>

typedef unsigned short u16;
typedef float f32x4 __attribute__((ext_vector_type(4)));
typedef __bf16 bf16x8 __attribute__((ext_vector_type(8)));

#define B_ 8
#define N_ 4096
#define C_ 256
#define NKV 256

__device__ inline u16 f2bf(float f) {
    union { float f; unsigned u; } v; v.f = f;
    unsigned r = v.u + 0x7FFF + ((v.u >> 16) & 1);
    return (u16)(r >> 16);
}

// ---------------- prep: weights -> bf16 (torch [out,in] layout kept as Bt[N][K]) ----------------
__global__ __launch_bounds__(256) void prep_w(
    const float* __restrict__ qw, const float* __restrict__ kvw,
    const float* __restrict__ pw, const float* __restrict__ srw,
    u16* __restrict__ wq, u16* __restrict__ wkv, u16* __restrict__ wp, u16* __restrict__ wsr)
{
    int t = blockIdx.x * 256 + threadIdx.x;
    int stride = gridDim.x * 256;
    for (int i = t; i < 65536; i += stride) { wq[i] = f2bf(qw[i]); wp[i] = f2bf(pw[i]); }
    for (int i = t; i < 131072; i += stride) wkv[i] = f2bf(kvw[i]);
    // wsr[o][(kh*4+kw)*256 + ci] = srw[o][ci][kh][kw]
    for (int i = t; i < 1048576; i += stride) {
        int o = i >> 12, k = i & 4095;
        int ci = k & 255, khkw = k >> 8;
        wsr[i] = f2bf(srw[(size_t)(o * 256 + ci) * 16 + khkw]);
    }
}

// ---------------- prep: x -> bf16 [B*N][C]  and  im2col patches [B*256][4096] ----------------
__global__ __launch_bounds__(256) void prep_x(
    const float* __restrict__ x, u16* __restrict__ xb, u16* __restrict__ patches)
{
    size_t base = ((size_t)blockIdx.x * 256 + threadIdx.x) * 4;
    float4 v = *(const float4*)(x + base);
    ushort4 o;
    o.x = f2bf(v.x); o.y = f2bf(v.y); o.z = f2bf(v.z); o.w = f2bf(v.w);
    *(ushort4*)(xb + base) = o;
    int c = (int)(base & 255);
    int n = (int)((base >> 8) & 4095);
    int b = (int)(base >> 20);
    int hh = n >> 6, ww = n & 63;
    int p = (hh >> 2) * 16 + (ww >> 2);
    int k = ((hh & 3) * 4 + (ww & 3)) * 256 + c;
    *(ushort4*)(patches + (size_t)(b * 256 + p) * 4096 + k) = o;
}

// ---------------- generic 128x128 bf16 MFMA GEMM:  out = A[M,K] @ Bt[N,K]^T (+bias) ----------------
// OUTMODE: 0 = f32 out + bias, 1 = bf16 out + bias, 2 = f32 split-K partial (offset z*M*N, no bias)
template<int OUTMODE>
__global__ __launch_bounds__(256, 2) void gemm128(
    const u16* __restrict__ A, const u16* __restrict__ Bt,
    const float* __restrict__ bias, void* __restrict__ outp,
    int M, int Nn, int K, int kchunk)
{
    __shared__ __align__(16) u16 As[128 * 40];
    __shared__ __align__(16) u16 Bs[128 * 40];
    const int tid = threadIdx.x;
    const int bm = blockIdx.x, bn = blockIdx.y, bz = blockIdx.z;
    const int k0 = bz * kchunk;
    const int wid = tid >> 6, lane = tid & 63;
    const int wr = wid >> 1, wc = wid & 1;
    const int lrow = lane & 15, lkg = lane >> 4;

    f32x4 acc[4][4] = {};

    const int rS = tid >> 2, cS = (tid & 3) * 8;
    const u16* aSrc = A  + (size_t)(bm * 128 + rS) * K + k0 + cS;
    const u16* bSrc = Bt + (size_t)(bn * 128 + rS) * K + k0 + cS;
    u16* aDst = As + rS * 40 + cS;
    u16* bDst = Bs + rS * 40 + cS;

    for (int kk = 0; kk < kchunk; kk += 32) {
        *(int4*)aDst             = *(const int4*)(aSrc + kk);
        *(int4*)(aDst + 64 * 40) = *(const int4*)(aSrc + (size_t)64 * K + kk);
        *(int4*)bDst             = *(const int4*)(bSrc + kk);
        *(int4*)(bDst + 64 * 40) = *(const int4*)(bSrc + (size_t)64 * K + kk);
        __syncthreads();
        bf16x8 af[4], bff[4];
#pragma unroll
        for (int i = 0; i < 4; ++i) {
            af[i]  = *(const bf16x8*)(As + (wr * 64 + i * 16 + lrow) * 40 + lkg * 8);
            bff[i] = *(const bf16x8*)(Bs + (wc * 64 + i * 16 + lrow) * 40 + lkg * 8);
        }
#pragma unroll
        for (int i = 0; i < 4; ++i)
#pragma unroll
            for (int j = 0; j < 4; ++j)
                acc[i][j] = __builtin_amdgcn_mfma_f32_16x16x32_bf16(af[i], bff[j], acc[i][j], 0, 0, 0);
        __syncthreads();
    }

    const int row0 = bm * 128 + wr * 64;
    const int col0 = bn * 128 + wc * 64;
    if constexpr (OUTMODE == 2) {
        float* o = (float*)outp + (size_t)bz * M * Nn;
#pragma unroll
        for (int i = 0; i < 4; ++i)
#pragma unroll
            for (int j = 0; j < 4; ++j)
#pragma unroll
                for (int reg = 0; reg < 4; ++reg)
                    o[(size_t)(row0 + i * 16 + lkg * 4 + reg) * Nn + col0 + j * 16 + lrow] = acc[i][j][reg];
    } else {
#pragma unroll
        for (int j = 0; j < 4; ++j) {
            const int col = col0 + j * 16 + lrow;
            const float bv = bias[col];
#pragma unroll
            for (int i = 0; i < 4; ++i)
#pragma unroll
                for (int reg = 0; reg < 4; ++reg) {
                    const size_t idx = (size_t)(row0 + i * 16 + lkg * 4 + reg) * Nn + col;
                    const float val = acc[i][j][reg] + bv;
                    if constexpr (OUTMODE == 1) ((u16*)outp)[idx] = f2bf(val);
                    else                        ((float*)outp)[idx] = val;
                }
        }
    }
}

// ---------------- LN over conv partial sums: xsr = LN(sum_z part + sr_b) -> bf16 ----------------
__global__ __launch_bounds__(256) void ln_kernel(
    const float* __restrict__ part, const float* __restrict__ srb,
    const float* __restrict__ g, const float* __restrict__ bb, u16* __restrict__ out)
{
    const int row = blockIdx.x, c = threadIdx.x;
    const size_t idx = (size_t)row * 256 + c;
    float v = srb[c] + part[idx] + part[idx + 524288] + part[idx + 2 * 524288] + part[idx + 3 * 524288];
    float s = v;
#pragma unroll
    for (int m = 1; m < 64; m <<= 1) s += __shfl_xor(s, m);
    __shared__ float red[4];
    if ((c & 63) == 0) red[c >> 6] = s;
    __syncthreads();
    float tot = red[0] + red[1] + red[2] + red[3];
    float mu = tot * (1.0f / 256.0f);
    float d = v - mu;
    float s2 = d * d;
#pragma unroll
    for (int m = 1; m < 64; m <<= 1) s2 += __shfl_xor(s2, m);
    __syncthreads();
    if ((c & 63) == 0) red[c >> 6] = s2;
    __syncthreads();
    float var = (red[0] + red[1] + red[2] + red[3]) * (1.0f / 256.0f);
    out[idx] = f2bf(d * rsqrtf(var + 1e-5f) * g[c] + bb[c]);
}

// ---------------- fused attention: per (b, h, 64-query tile) ----------------
// qbuf: bf16 [B*N][C]; kvbuf: bf16 [B*256][512] (k at col h*32, v at 256+h*32); obuf: bf16 [B*N][C]
__global__ __launch_bounds__(256, 2) void attn_kernel(
    const u16* __restrict__ qbuf, const u16* __restrict__ kvbuf, u16* __restrict__ obuf)
{
    __shared__ __align__(16) u16 lds[25344];
    const int qt = blockIdx.x, h = blockIdx.y, b = blockIdx.z;
    const int tid = threadIdx.x;
    const int wid = tid >> 6, lane = tid & 63;
    const int lrow = lane & 15, lkg = lane >> 4;
    const int QOFF = 0, KOFF = 2560, VOFF = 16896, POFF = 0;

    // stage q tile [64][32] (A layout, stride 40)
    {
        int r = tid >> 2, ch = (tid & 3) * 8;
        *(int4*)(lds + QOFF + r * 40 + ch) =
            *(const int4*)(qbuf + (size_t)(b * 4096 + qt * 64 + r) * 256 + h * 32 + ch);
    }
    // stage k [256][32] (Bt layout, stride 40)
#pragma unroll
    for (int pass = 0; pass < 4; ++pass) {
        int p = (tid >> 2) + pass * 64, ch = (tid & 3) * 8;
        *(int4*)(lds + KOFF + p * 40 + ch) =
            *(const int4*)(kvbuf + (size_t)(b * 256 + p) * 512 + h * 32 + ch);
    }
    // stage V^T [32][264]: Vt[d][p] = v[p][d]
    {
        const u16* vs = kvbuf + (size_t)(b * 256 + tid) * 512 + 256 + h * 32;
#pragma unroll
        for (int j = 0; j < 8; ++j) {
            ushort4 vv = *(const ushort4*)(vs + j * 4);
            lds[VOFF + (j * 4 + 0) * 264 + tid] = vv.x;
            lds[VOFF + (j * 4 + 1) * 264 + tid] = vv.y;
            lds[VOFF + (j * 4 + 2) * 264 + tid] = vv.z;
            lds[VOFF + (j * 4 + 3) * 264 + tid] = vv.w;
        }
    }
    __syncthreads();

    // S = q k^T : wave handles 16 q-rows, acc[nf] covers cols nf*16..
    f32x4 acc[16] = {};
    bf16x8 aq = *(const bf16x8*)(lds + QOFF + (wid * 16 + lrow) * 40 + lkg * 8);
#pragma unroll
    for (int nf = 0; nf < 16; ++nf) {
        bf16x8 bk = *(const bf16x8*)(lds + KOFF + (nf * 16 + lrow) * 40 + lkg * 8);
        acc[nf] = __builtin_amdgcn_mfma_f32_16x16x32_bf16(aq, bk, acc[nf], 0, 0, 0);
    }

    // softmax over each row (scale folded into exp2)
    const float cexp = 0.17677669529663687f * 1.4426950408889634f;
    float inv[4];
#pragma unroll
    for (int reg = 0; reg < 4; ++reg) {
        float m = acc[0][reg];
#pragma unroll
        for (int nf = 1; nf < 16; ++nf) m = fmaxf(m, acc[nf][reg]);
        m = fmaxf(m, __shfl_xor(m, 1)); m = fmaxf(m, __shfl_xor(m, 2));
        m = fmaxf(m, __shfl_xor(m, 4)); m = fmaxf(m, __shfl_xor(m, 8));
        float s = 0.f;
#pragma unroll
        for (int nf = 0; nf < 16; ++nf) {
            float p = exp2f((acc[nf][reg] - m) * cexp);
            acc[nf][reg] = p; s += p;
        }
        s += __shfl_xor(s, 1); s += __shfl_xor(s, 2);
        s += __shfl_xor(s, 4); s += __shfl_xor(s, 8);
        inv[reg] = 1.0f / s;
    }
    __syncthreads();  // all waves done reading q/k before P overwrites that region

    // write P (unnormalized, bf16) rows wid*16.. [64][264]
#pragma unroll
    for (int nf = 0; nf < 16; ++nf)
#pragma unroll
        for (int reg = 0; reg < 4; ++reg)
            lds[POFF + (wid * 16 + lkg * 4 + reg) * 264 + nf * 16 + lrow] = f2bf(acc[nf][reg]);
    __syncthreads();

    // O = P @ V : K=256 in 8 steps
    f32x4 o0 = {}, o1 = {};
#pragma unroll
    for (int ks = 0; ks < 8; ++ks) {
        bf16x8 pa = *(const bf16x8*)(lds + POFF + (wid * 16 + lrow) * 264 + ks * 32 + lkg * 8);
        bf16x8 v0 = *(const bf16x8*)(lds + VOFF + lrow * 264 + ks * 32 + lkg * 8);
        bf16x8 v1 = *(const bf16x8*)(lds + VOFF + (16 + lrow) * 264 + ks * 32 + lkg * 8);
        o0 = __builtin_amdgcn_mfma_f32_16x16x32_bf16(pa, v0, o0, 0, 0, 0);
        o1 = __builtin_amdgcn_mfma_f32_16x16x32_bf16(pa, v1, o1, 0, 0, 0);
    }
    const size_t orow0 = (size_t)(b * 4096 + qt * 64 + wid * 16);
#pragma unroll
    for (int reg = 0; reg < 4; ++reg) {
        int rr = lkg * 4 + reg;
        float sc = inv[reg];
        obuf[(orow0 + rr) * 256 + h * 32 + lrow]      = f2bf(o0[reg] * sc);
        obuf[(orow0 + rr) * 256 + h * 32 + 16 + lrow] = f2bf(o1[reg] * sc);
    }
}

extern "C" void kernel_launch(void* const* d_in, const int* in_sizes, int n_in,
                              void* d_out, int out_size, void* d_ws, size_t ws_size,
                              hipStream_t stream)
{
    (void)in_sizes; (void)n_in; (void)out_size; (void)ws_size;
    const float* x   = (const float*)d_in[0];
    const float* qw  = (const float*)d_in[3];
    const float* qb  = (const float*)d_in[4];
    const float* kvw = (const float*)d_in[5];
    const float* kvb = (const float*)d_in[6];
    const float* srw = (const float*)d_in[7];
    const float* srb = (const float*)d_in[8];
    const float* lng = (const float*)d_in[9];
    const float* lnb = (const float*)d_in[10];
    const float* pw  = (const float*)d_in[11];
    const float* pb  = (const float*)d_in[12];

    char* ws = (char*)d_ws;
    u16*   xb      = (u16*)(ws + 0);          // 16.78 MB  x as bf16 [32768][256]
    u16*   patches = (u16*)(ws + 16777216);   // 16.78 MB  im2col [2048][4096]; later reused as attn_out
    float* part    = (float*)(ws + 33554432); //  8.39 MB  conv split-K partials [4][2048][256]
    u16*   wsr     = (u16*)(ws + 41943040);   //  2.10 MB
    u16*   wqb     = (u16*)(ws + 44040192);
    u16*   wkvb    = (u16*)(ws + 44171264);
    u16*   wpb     = (u16*)(ws + 44433408);
    u16*   xsr     = (u16*)(ws + 44564480);   //  1.05 MB  LN output bf16 [2048][256]
    u16*   kvo     = (u16*)(ws + 45613056);   //  2.10 MB  kv bf16 [2048][512]
    u16*   qbuf    = (u16*)d_out;             // q bf16 [32768][256] in d_out scratch (overwritten by proj)

    prep_w<<<1024, 256, 0, stream>>>(qw, kvw, pw, srw, wqb, wkvb, wpb, wsr);
    prep_x<<<8192, 256, 0, stream>>>(x, xb, patches);
    // conv as GEMM, split-K x4 -> f32 partials
    gemm128<2><<<dim3(16, 2, 4), 256, 0, stream>>>(patches, wsr, nullptr, part, 2048, 256, 4096, 1024);
    ln_kernel<<<2048, 256, 0, stream>>>(part, srb, lng, lnb, xsr);
    gemm128<1><<<dim3(16, 4, 1), 256, 0, stream>>>(xsr, wkvb, kvb, kvo, 2048, 512, 256, 256);
    gemm128<1><<<dim3(256, 2, 1), 256, 0, stream>>>(xb, wqb, qb, qbuf, 32768, 256, 256, 256);
    attn_kernel<<<dim3(64, 8, 8), 256, 0, stream>>>(qbuf, kvo, patches);
    gemm128<0><<<dim3(256, 2, 1), 256, 0, stream>>>(patches, wpb, pb, d_out, 32768, 256, 256, 256);
}